// Round 5
// baseline (3441.387 us; speedup 1.0000x reference)
//
#include <hip/hip_runtime.h>
#include <stdint.h>

#define B_ 8
#define N_ 4096
#define C_ 128
#define OSEM 13
#define OINS 5
#define KNN 30
#define NSC 48  // screened candidates (f32) rescored in f64

typedef unsigned short u16;
typedef unsigned int u32;
typedef unsigned long long u64;

// mode: 0 = device tensors are bf16, 1 = device tensors are fp32
__device__ __forceinline__ float bf2f(u16 v) {
  u32 u = ((u32)v) << 16;
  return __uint_as_float(u);
}
__device__ __forceinline__ u16 f2bf(float f) {
  u32 u = __float_as_uint(f);
  u32 r = (u + 0x7FFFu + ((u >> 16) & 1u)) >> 16;  // RNE
  return (u16)r;
}
__device__ __forceinline__ u32 monof(float d) {
  u32 u = __float_as_uint(d);
  return (u & 0x80000000u) ? ~u : (u | 0x80000000u);
}
__device__ __forceinline__ u64 monod(double d) {
  u64 u = (u64)__double_as_longlong(d);
  return (u & 0x8000000000000000ull) ? ~u : (u | 0x8000000000000000ull);
}
__device__ __forceinline__ u64 shfl_xor_u64(u64 v, int m) {
  u32 lo = (u32)__shfl_xor((int)(u32)v, m, 64);
  u32 hi = (u32)__shfl_xor((int)(u32)(v >> 32), m, 64);
  return ((u64)hi << 32) | lo;
}
__device__ __forceinline__ u64 shfl_u64(u64 v, int src) {
  u32 lo = (u32)__shfl((int)(u32)v, src, 64);
  u32 hi = (u32)__shfl((int)(u32)(v >> 32), src, 64);
  return ((u64)hi << 32) | lo;
}

template <int M>
__device__ __forceinline__ float ldv(const void* p, size_t i) {
  if (M == 0) return bf2f(((const u16*)p)[i]);
  return ((const float*)p)[i];
}
template <int M>
__device__ __forceinline__ double ldvd(const void* p, size_t i) {
  return (double)ldv<M>(p, i);
}
template <int M>
__device__ __forceinline__ void stv(void* p, size_t i, float v) {
  if (M == 0) ((u16*)p)[i] = f2bf(v);
  else ((float*)p)[i] = v;
}
template <int M>
__device__ __forceinline__ void ld8(const void* p, size_t i, float* o) {
  if (M == 0) {
    uint4 u = *(const uint4*)((const u16*)p + i);
    o[0] = __uint_as_float(u.x << 16); o[1] = __uint_as_float(u.x & 0xFFFF0000u);
    o[2] = __uint_as_float(u.y << 16); o[3] = __uint_as_float(u.y & 0xFFFF0000u);
    o[4] = __uint_as_float(u.z << 16); o[5] = __uint_as_float(u.z & 0xFFFF0000u);
    o[6] = __uint_as_float(u.w << 16); o[7] = __uint_as_float(u.w & 0xFFFF0000u);
  } else {
    const float4* f = (const float4*)((const float*)p + i);
    float4 a = f[0], b = f[1];
    o[0] = a.x; o[1] = a.y; o[2] = a.z; o[3] = a.w;
    o[4] = b.x; o[5] = b.y; o[6] = b.z; o[7] = b.w;
  }
}

// ---------------------------------------------------------------------------
// Sniff dtype from data (0=bf16, 1=fp32).
// ---------------------------------------------------------------------------
__global__ void k_sniff(const void* fsem, u32* flag) {
  __shared__ int s[64];
  int lane = threadIdx.x;
  const u16* p = (const u16*)fsem;
  int cnt = 0;
#pragma unroll 8
  for (int i = 0; i < 64; ++i) {
    u16 v = p[2 * (lane * 64 + i)];
    u32 e = (v >> 7) & 0xFF;
    cnt += (e >= 0x60 && e <= 0x9F) ? 1 : 0;
  }
  s[lane] = cnt;
  __syncthreads();
  if (lane == 0) {
    int t = 0;
    for (int i = 0; i < 64; ++i) t += s[i];
    flag[0] = (t >= 2458) ? 0u : 1u;  // bf16 ~4096, fp32 ~1024
  }
}

// ---------------------------------------------------------------------------
// Transpose f_sem[b][c][n] -> fT[b][n][c] for coalesced neighbor gathers.
// ---------------------------------------------------------------------------
template <typename T, int M>
__global__ __launch_bounds__(256) void k_transpose(const u32* flag,
                                                   const void* src_,
                                                   void* dst_) {
  if (*flag != (u32)M) return;
  __shared__ T t[64][65];
  const T* src0 = (const T*)src_;
  T* dst0 = (T*)dst_;
  int b = blockIdx.z, c0 = blockIdx.y * 64, n0 = blockIdx.x * 64;
  int tid = threadIdx.x, j = tid & 63, i0 = tid >> 6;
  const T* src = src0 + (size_t)(b * C_ + c0) * N_ + n0;
#pragma unroll
  for (int k = 0; k < 16; ++k) {
    int i = k * 4 + i0;
    t[i][j] = src[(size_t)i * N_ + j];
  }
  __syncthreads();
  T* dst = dst0 + ((size_t)b * N_ + n0) * C_ + c0;
#pragma unroll
  for (int k = 0; k < 16; ++k) {
    int nl = k * 4 + i0;
    dst[(size_t)nl * C_ + j] = t[j][nl];
  }
}

// ---------------------------------------------------------------------------
// Fused (ALL f64): adapted = W_adapt@f_sem ; h = relu(a*g+b) ; fs = f_ins+h ;
// e = W_ins@fs ; sq = sum(e*e). Emits e_ins output + q32 (f32 screening
// records) + q64 (f64 exact records).
// Tile: 128 cols x 128 c. Thread (tx=tid&15, ty=tid>>4): acc[8c][8n] f64.
// K-chunks of 32 (xs,wt f64 = 64KB LDS); then fs -> LDS as f32 hi/lo pairs
// (exact split) in two column-halves; 64 threads compute e per column.
// ---------------------------------------------------------------------------
template <int M>
__global__ __launch_bounds__(256) void k_fused(
    const u32* flag, const void* fsem, const void* fins, const void* Wad,
    const void* bad, const void* gad, const void* bead, const void* Wins,
    const void* bins, float* __restrict__ q32, double* __restrict__ q64,
    void* oute) {
  if (*flag != (u32)M) return;
  __shared__ __align__(16) char smem[65536];
  double* xs = (double*)smem;            // [32][128] f64 (32KB)
  double* wt = (double*)(smem + 32768);  // [32][128] f64 (32KB)
  float* fsh = (float*)smem;             // phase 2: [128][64] hi (32KB)
  float* fsl = (float*)(smem + 32768);   // phase 2: [128][64] lo (32KB)

  int tid = threadIdx.x, tx = tid & 15, ty = tid >> 4;
  int b = blockIdx.y, n0 = blockIdx.x * 128;

  double acc[8][8];
#pragma unroll
  for (int i = 0; i < 8; ++i)
#pragma unroll
    for (int j = 0; j < 8; ++j) acc[i][j] = 0.0;

  for (int kk = 0; kk < 128; kk += 32) {
    __syncthreads();
    // stage x chunk: 32 rows x 128 cols, f64
#pragma unroll
    for (int it = 0; it < 2; ++it) {
      int g = it * 256 + tid;  // 512 groups of 8
      int r = g >> 4, c8 = g & 15;
      float v[8];
      ld8<M>(fsem, (size_t)(b * C_ + kk + r) * N_ + n0 + c8 * 8, v);
#pragma unroll
      for (int j = 0; j < 8; ++j) xs[r * 128 + c8 * 8 + j] = (double)v[j];
    }
    // stage W^T chunk: wt[k][c] = Wad[c][kk+k], f64
#pragma unroll
    for (int it = 0; it < 16; ++it) {
      int f = it * 256 + tid;
      int k = f >> 7, c = f & 127;
      wt[k * 128 + c] = ldvd<M>(Wad, (size_t)c * C_ + kk + k);
    }
    __syncthreads();
#pragma unroll 2
    for (int k = 0; k < 32; ++k) {
      double xv[8], wv[8];
#pragma unroll
      for (int j = 0; j < 8; ++j) xv[j] = xs[k * 128 + tx * 8 + j];
#pragma unroll
      for (int i = 0; i < 8; ++i) wv[i] = wt[k * 128 + ty * 8 + i];
#pragma unroll
      for (int i = 0; i < 8; ++i)
#pragma unroll
        for (int j = 0; j < 8; ++j) acc[i][j] = fma(wv[i], xv[j], acc[i][j]);
    }
  }

  // epilogue in registers: acc -> fs (f64)
#pragma unroll
  for (int i = 0; i < 8; ++i) {
    int c = ty * 8 + i;
    double ba = ldvd<M>(bad, c), ga = ldvd<M>(gad, c), be = ldvd<M>(bead, c);
    float ff[8];
    ld8<M>(fins, (size_t)(b * C_ + c) * N_ + n0 + tx * 8, ff);
#pragma unroll
    for (int j = 0; j < 8; ++j) {
      double a = acc[i][j] + ba;
      double h = a * ga + be;
      h = h > 0.0 ? h : 0.0;
      acc[i][j] = (double)ff[j] + h;
    }
  }
  __syncthreads();  // all GEMM LDS reads done; reuse as fsh/fsl

  // two column-half passes: fs -> LDS (exact f32 hi/lo), e per column
#pragma unroll 1
  for (int p = 0; p < 2; ++p) {
    if ((tx >> 3) == p) {
      int nq = tx * 8 - p * 64;  // 0..56
#pragma unroll
      for (int i = 0; i < 8; ++i) {
        int c = ty * 8 + i;
#pragma unroll
        for (int j = 0; j < 8; ++j) {
          double fs = acc[i][j];
          float hi = (float)fs;
          fsh[c * 64 + nq + j] = hi;
          fsl[c * 64 + nq + j] = (float)(fs - (double)hi);
        }
      }
    }
    __syncthreads();
    if (tid < 64) {
      int n = n0 + p * 64 + tid;
      double e[5] = {0.0, 0.0, 0.0, 0.0, 0.0};
#pragma unroll 4
      for (int c = 0; c < 128; ++c) {
        double fs = (double)fsh[c * 64 + tid] + (double)fsl[c * 64 + tid];
#pragma unroll
        for (int o = 0; o < 5; ++o)
          e[o] = fma(ldvd<M>(Wins, (size_t)o * C_ + c), fs, e[o]);
      }
      double sq = 0.0;
#pragma unroll
      for (int o = 0; o < 5; ++o) {
        e[o] = e[o] + ldvd<M>(bins, o);
        sq = fma(e[o], e[o], sq);
        stv<M>(oute, (size_t)(b * OINS + o) * N_ + n, (float)e[o]);
      }
      size_t row = (size_t)b * N_ + n;
      float* qp = q32 + row * 8;
      qp[0] = (float)e[0]; qp[1] = (float)e[1]; qp[2] = (float)e[2];
      qp[3] = (float)e[3]; qp[4] = (float)e[4]; qp[5] = (float)sq;
      qp[6] = 0.f; qp[7] = 0.f;
      double* qd = q64 + row * 8;
      qd[0] = e[0]; qd[1] = e[1]; qd[2] = e[2]; qd[3] = e[3]; qd[4] = e[4];
      qd[5] = sq; qd[6] = 0.0; qd[7] = 0.0;
    }
    __syncthreads();
  }
}

// ---------------------------------------------------------------------------
// KNN: f32 screening top-48 (exact register argmin extraction) -> f64
// rescore of the 48 -> exact f64 top-30 set -> gather/max + W_sem proj.
// ---------------------------------------------------------------------------
template <int M>
__global__ __launch_bounds__(256) void k_knn_out(
    const u32* flag, const float* __restrict__ q32,
    const double* __restrict__ q64, const void* fsem, const void* fT,
    int useFT, const void* Wsem, const void* bsem, void* outv) {
  if (*flag != (u32)M) return;
  __shared__ u64 red[2][4];
  __shared__ u32 idxs[NSC];
  __shared__ u32 idxf[32];
  __shared__ float fls[2][128];
  __shared__ float wsm[13 * 129];
  __shared__ float bsm[16];

  int tid = threadIdx.x, wid = tid >> 6, lane = tid & 63;
  for (int i = tid; i < 13 * 128; i += 256)
    wsm[(i >> 7) * 129 + (i & 127)] = ldv<M>(Wsem, i);
  if (tid < OSEM) bsm[tid] = ldv<M>(bsem, tid);
  __syncthreads();

#pragma unroll 1
  for (int rr = 0; rr < 64; ++rr) {
    int row = rr * 512 + (int)blockIdx.x;  // 512 blocks
    int b = row >> 12, n = row & (N_ - 1);
    const float* qb = q32 + (((size_t)b) << 12) * 8;
    const float* qr = q32 + (size_t)row * 8;
    float E0 = qr[0], E1 = qr[1], E2 = qr[2], E3 = qr[3], E4 = qr[4],
          SQ = qr[5];

    // f32 screening: per-thread 16 candidates, 48 argmin extractions
    u64 keys[16];
    u64 lm = ~0ull;
#pragma unroll
    for (int c16 = 0; c16 < 16; ++c16) {
      int m = c16 * 256 + tid;
      const float* qm = qb + (size_t)m * 8;
      float4 A = *(const float4*)qm;
      float4 Bv = *(const float4*)(qm + 4);
      float dot = E0 * A.x;
      dot = fmaf(E1, A.y, dot);
      dot = fmaf(E2, A.z, dot);
      dot = fmaf(E3, A.w, dot);
      dot = fmaf(E4, Bv.x, dot);
      float d = (SQ - 2.0f * dot) + Bv.y;
      u64 key = ((u64)monof(d) << 32) | (u32)m;
      keys[c16] = key;
      lm = key < lm ? key : lm;
    }
#pragma unroll 1
    for (int it = 0; it < NSC; ++it) {
      u64 wmin = lm;
#pragma unroll
      for (int off = 32; off > 0; off >>= 1) {
        u64 o = shfl_xor_u64(wmin, off);
        wmin = o < wmin ? o : wmin;
      }
      if (lane == 0) red[it & 1][wid] = wmin;
      __syncthreads();
      u64 g = red[it & 1][0];
      u64 g1 = red[it & 1][1]; g = g1 < g ? g1 : g;
      u64 g2 = red[it & 1][2]; g = g2 < g ? g2 : g;
      u64 g3 = red[it & 1][3]; g = g3 < g ? g3 : g;
      if (tid == 0) idxs[it] = (u32)g & (N_ - 1);
      if (lm == g) {  // unique owner
#pragma unroll
        for (int j = 0; j < 16; ++j)
          if (keys[j] == g) keys[j] = ~0ull;
        lm = ~0ull;
#pragma unroll
        for (int j = 0; j < 16; ++j) lm = keys[j] < lm ? keys[j] : lm;
      }
    }
    __syncthreads();

    // f64 rescore of the 48 in wave 0: exact (d, m) rank, keep rank < 30
    if (tid < 64) {
      const double* qdb = q64 + (((size_t)b) << 12) * 8;
      const double* qdr = q64 + (size_t)row * 8;
      double D0 = qdr[0], D1 = qdr[1], D2 = qdr[2], D3 = qdr[3], D4 = qdr[4],
             DS = qdr[5];
      u64 key = ~0ull;
      u32 myid = 0;
      if (tid < NSC) {
        myid = idxs[tid];
        const double* qm = qdb + (size_t)myid * 8;
        double dot = D0 * qm[0];
        dot = fma(D1, qm[1], dot);
        dot = fma(D2, qm[2], dot);
        dot = fma(D3, qm[3], dot);
        dot = fma(D4, qm[4], dot);
        double d = (DS - 2.0 * dot) + qm[5];
        key = (monod(d) & ~0xFFFull) | myid;
      }
      int rank = 0;
#pragma unroll 8
      for (int j = 0; j < NSC; ++j) {
        u64 kj = shfl_u64(key, j);
        rank += (kj < key) ? 1 : 0;
      }
      if (tid < NSC && rank < KNN) idxf[rank] = myid;
    }
    __syncthreads();

    // gather/max: 256 threads = 2 halves x 128 channels; 15 neighbors each
    int c = tid & 127, half = tid >> 7;
    float mx = -__builtin_inff();
    if (useFT) {
#pragma unroll
      for (int k = 0; k < 15; ++k) {
        int id = (int)idxf[half * 15 + k];
        mx = fmaxf(mx, ldv<M>(fT, (size_t)(b * N_ + id) * C_ + c));
      }
    } else {
#pragma unroll
      for (int k = 0; k < 15; ++k) {
        int id = (int)idxf[half * 15 + k];
        mx = fmaxf(mx, ldv<M>(fsem, ((size_t)b * C_ + c) * N_ + id));
      }
    }
    fls[half][c] = mx;
    __syncthreads();

    if (tid < OSEM) {
      float s = 0.f;
#pragma unroll 8
      for (int cc = 0; cc < C_; ++cc)
        s = fmaf(wsm[tid * 129 + cc], fmaxf(fls[0][cc], fls[1][cc]), s);
      s = __fadd_rn(s, bsm[tid]);
      stv<M>(outv, ((size_t)b * OSEM + tid) * N_ + n, s);
    }
    __syncthreads();  // LDS reused next row
  }
}

// ---------------------------------------------------------------------------
extern "C" void kernel_launch(void* const* d_in, const int* in_sizes, int n_in,
                              void* d_out, int out_size, void* d_ws,
                              size_t ws_size, hipStream_t stream) {
  (void)in_sizes; (void)n_in; (void)out_size;
  const void* fsem = d_in[0];
  const void* fins = d_in[1];
  const void* Wad = d_in[2];
  const void* bad = d_in[3];
  const void* gad = d_in[4];
  const void* bead = d_in[5];
  const void* Wins = d_in[6];
  const void* bins = d_in[7];
  const void* Wsem = d_in[8];
  const void* bsem = d_in[9];

  char* ws = (char*)d_ws;
  u32* flag = (u32*)ws;                    // @0
  float* q32 = (float*)(ws + (1 << 20));   // @1MB, 1MB
  double* q64 = (double*)(ws + (2 << 20)); // @2MB, 2MB
  void* fT = (void*)(ws + (4 << 20));      // @4MB, up to 16MB
  int useFT = (ws_size >= (size_t)(21 << 20)) ? 1 : 0;

  void* oute_bf = (void*)((u16*)d_out + (size_t)B_ * OSEM * N_);
  void* oute_f32 = (void*)((float*)d_out + (size_t)B_ * OSEM * N_);

  k_sniff<<<1, 64, 0, stream>>>(fsem, flag);

  if (useFT) {
    k_transpose<u16, 0><<<dim3(64, 2, 8), 256, 0, stream>>>(flag, fsem, fT);
    k_transpose<float, 1><<<dim3(64, 2, 8), 256, 0, stream>>>(flag, fsem, fT);
  }
  k_fused<0><<<dim3(32, 8), 256, 0, stream>>>(flag, fsem, fins, Wad, bad, gad,
                                              bead, Wins, bins, q32, q64,
                                              oute_bf);
  k_fused<1><<<dim3(32, 8), 256, 0, stream>>>(flag, fsem, fins, Wad, bad, gad,
                                              bead, Wins, bins, q32, q64,
                                              oute_f32);
  k_knn_out<0><<<dim3(512), 256, 0, stream>>>(flag, q32, q64, fsem, fT, useFT,
                                              Wsem, bsem, d_out);
  k_knn_out<1><<<dim3(512), 256, 0, stream>>>(flag, q32, q64, fsem, fT, useFT,
                                              Wsem, bsem, d_out);
}

// Round 6
// 618.483 us; speedup vs baseline: 5.5642x; 5.5642x over previous
//
#include <hip/hip_runtime.h>
#include <stdint.h>

#define B_ 8
#define N_ 4096
#define C_ 128
#define OSEM 13
#define OINS 5
#define KNN 30
#define NSC 48   // f32-screened candidates, rescored in f64
#define ROWS 8   // rows per wave in k_knn

typedef unsigned short u16;
typedef unsigned int u32;
typedef unsigned long long u64;

__device__ __forceinline__ float bf2f(u16 v) {
  u32 u = ((u32)v) << 16;
  return __uint_as_float(u);
}
__device__ __forceinline__ u16 f2bf(float f) {
  u32 u = __float_as_uint(f);
  u32 r = (u + 0x7FFFu + ((u >> 16) & 1u)) >> 16;  // RNE
  return (u16)r;
}
__device__ __forceinline__ u32 monof(float d) {
  u32 u = __float_as_uint(d);
  return (u & 0x80000000u) ? ~u : (u | 0x80000000u);
}
__device__ __forceinline__ float unmonof(u32 p) {
  u32 u = (p & 0x80000000u) ? (p & 0x7FFFFFFFu) : ~p;
  return __uint_as_float(u);
}
__device__ __forceinline__ u64 monod(double d) {
  u64 u = (u64)__double_as_longlong(d);
  return (u & 0x8000000000000000ull) ? ~u : (u | 0x8000000000000000ull);
}
__device__ __forceinline__ int mbcnt64(u64 m) {
  return __builtin_amdgcn_mbcnt_hi((u32)(m >> 32),
                                   __builtin_amdgcn_mbcnt_lo((u32)m, 0));
}
__device__ __forceinline__ u64 shfl_u64(u64 v, int src) {
  u32 lo = (u32)__shfl((int)(u32)v, src, 64);
  u32 hi = (u32)__shfl((int)(u32)(v >> 32), src, 64);
  return ((u64)hi << 32) | lo;
}

template <int M>
__device__ __forceinline__ float ldv(const void* p, size_t i) {
  if (M == 0) return bf2f(((const u16*)p)[i]);
  return ((const float*)p)[i];
}
template <int M>
__device__ __forceinline__ double ldvd(const void* p, size_t i) {
  return (double)ldv<M>(p, i);
}
template <int M>
__device__ __forceinline__ void stv(void* p, size_t i, float v) {
  if (M == 0) ((u16*)p)[i] = f2bf(v);
  else ((float*)p)[i] = v;
}
template <int M>
__device__ __forceinline__ void ld8(const void* p, size_t i, float* o) {
  if (M == 0) {
    uint4 u = *(const uint4*)((const u16*)p + i);
    o[0] = __uint_as_float(u.x << 16); o[1] = __uint_as_float(u.x & 0xFFFF0000u);
    o[2] = __uint_as_float(u.y << 16); o[3] = __uint_as_float(u.y & 0xFFFF0000u);
    o[4] = __uint_as_float(u.z << 16); o[5] = __uint_as_float(u.z & 0xFFFF0000u);
    o[6] = __uint_as_float(u.w << 16); o[7] = __uint_as_float(u.w & 0xFFFF0000u);
  } else {
    const float4* f = (const float4*)((const float*)p + i);
    float4 a = f[0], b = f[1];
    o[0] = a.x; o[1] = a.y; o[2] = a.z; o[3] = a.w;
    o[4] = b.x; o[5] = b.y; o[6] = b.z; o[7] = b.w;
  }
}

// ---------------------------------------------------------------------------
// Sniff dtype from data (0=bf16, 1=fp32).
// ---------------------------------------------------------------------------
__global__ void k_sniff(const void* fsem, u32* flag) {
  __shared__ int s[64];
  int lane = threadIdx.x;
  const u16* p = (const u16*)fsem;
  int cnt = 0;
#pragma unroll 8
  for (int i = 0; i < 64; ++i) {
    u16 v = p[2 * (lane * 64 + i)];
    u32 e = (v >> 7) & 0xFF;
    cnt += (e >= 0x60 && e <= 0x9F) ? 1 : 0;
  }
  s[lane] = cnt;
  __syncthreads();
  if (lane == 0) {
    int t = 0;
    for (int i = 0; i < 64; ++i) t += s[i];
    flag[0] = (t >= 2458) ? 0u : 1u;  // bf16 ~4096, fp32 ~1024
  }
}

// ---------------------------------------------------------------------------
// Transpose f_sem[b][c][n] -> fT[b][n][c] as FLOAT for coalesced gathers.
// ---------------------------------------------------------------------------
template <typename T, int M>
__global__ __launch_bounds__(256) void k_transpose(const u32* flag,
                                                   const void* src_,
                                                   float* __restrict__ dst) {
  if (*flag != (u32)M) return;
  __shared__ float t[64][65];
  const T* src0 = (const T*)src_;
  int b = blockIdx.z, c0 = blockIdx.y * 64, n0 = blockIdx.x * 64;
  int tid = threadIdx.x, j = tid & 63, i0 = tid >> 6;
  const T* src = src0 + (size_t)(b * C_ + c0) * N_ + n0;
#pragma unroll
  for (int k = 0; k < 16; ++k) {
    int i = k * 4 + i0;
    t[i][j] = ldv<M>(src, (size_t)i * N_ + j);
  }
  __syncthreads();
  float* d = dst + ((size_t)b * N_ + n0) * C_ + c0;
#pragma unroll
  for (int k = 0; k < 16; ++k) {
    int nl = k * 4 + i0;
    d[(size_t)nl * C_ + j] = t[j][nl];
  }
}

// ---------------------------------------------------------------------------
// Fused (ALL f64, verified round 5): adapted = W_adapt@f_sem ; relu affine ;
// fs = f_ins + h ; e = W_ins@fs ; sq. Emits e_ins + q32 + q64 records.
// ---------------------------------------------------------------------------
template <int M>
__global__ __launch_bounds__(256) void k_fused(
    const u32* flag, const void* fsem, const void* fins, const void* Wad,
    const void* bad, const void* gad, const void* bead, const void* Wins,
    const void* bins, float* __restrict__ q32, double* __restrict__ q64,
    void* oute) {
  if (*flag != (u32)M) return;
  __shared__ __align__(16) char smem[65536];
  double* xs = (double*)smem;            // [32][128] f64 (32KB)
  double* wt = (double*)(smem + 32768);  // [32][128] f64 (32KB)
  float* fsh = (float*)smem;             // phase 2: [128][64] hi (32KB)
  float* fsl = (float*)(smem + 32768);   // phase 2: [128][64] lo (32KB)

  int tid = threadIdx.x, tx = tid & 15, ty = tid >> 4;
  int b = blockIdx.y, n0 = blockIdx.x * 128;

  double acc[8][8];
#pragma unroll
  for (int i = 0; i < 8; ++i)
#pragma unroll
    for (int j = 0; j < 8; ++j) acc[i][j] = 0.0;

  for (int kk = 0; kk < 128; kk += 32) {
    __syncthreads();
#pragma unroll
    for (int it = 0; it < 2; ++it) {
      int g = it * 256 + tid;
      int r = g >> 4, c8 = g & 15;
      float v[8];
      ld8<M>(fsem, (size_t)(b * C_ + kk + r) * N_ + n0 + c8 * 8, v);
#pragma unroll
      for (int j = 0; j < 8; ++j) xs[r * 128 + c8 * 8 + j] = (double)v[j];
    }
#pragma unroll
    for (int it = 0; it < 16; ++it) {
      int f = it * 256 + tid;
      int k = f >> 7, c = f & 127;
      wt[k * 128 + c] = ldvd<M>(Wad, (size_t)c * C_ + kk + k);
    }
    __syncthreads();
#pragma unroll 2
    for (int k = 0; k < 32; ++k) {
      double xv[8], wv[8];
#pragma unroll
      for (int j = 0; j < 8; ++j) xv[j] = xs[k * 128 + tx * 8 + j];
#pragma unroll
      for (int i = 0; i < 8; ++i) wv[i] = wt[k * 128 + ty * 8 + i];
#pragma unroll
      for (int i = 0; i < 8; ++i)
#pragma unroll
        for (int j = 0; j < 8; ++j) acc[i][j] = fma(wv[i], xv[j], acc[i][j]);
    }
  }

#pragma unroll
  for (int i = 0; i < 8; ++i) {
    int c = ty * 8 + i;
    double ba = ldvd<M>(bad, c), ga = ldvd<M>(gad, c), be = ldvd<M>(bead, c);
    float ff[8];
    ld8<M>(fins, (size_t)(b * C_ + c) * N_ + n0 + tx * 8, ff);
#pragma unroll
    for (int j = 0; j < 8; ++j) {
      double a = acc[i][j] + ba;
      double h = a * ga + be;
      h = h > 0.0 ? h : 0.0;
      acc[i][j] = (double)ff[j] + h;
    }
  }
  __syncthreads();

#pragma unroll 1
  for (int p = 0; p < 2; ++p) {
    if ((tx >> 3) == p) {
      int nq = tx * 8 - p * 64;
#pragma unroll
      for (int i = 0; i < 8; ++i) {
        int c = ty * 8 + i;
#pragma unroll
        for (int j = 0; j < 8; ++j) {
          double fs = acc[i][j];
          float hi = (float)fs;
          fsh[c * 64 + nq + j] = hi;
          fsl[c * 64 + nq + j] = (float)(fs - (double)hi);
        }
      }
    }
    __syncthreads();
    if (tid < 64) {
      int n = n0 + p * 64 + tid;
      double e[5] = {0.0, 0.0, 0.0, 0.0, 0.0};
#pragma unroll 4
      for (int c = 0; c < 128; ++c) {
        double fs = (double)fsh[c * 64 + tid] + (double)fsl[c * 64 + tid];
#pragma unroll
        for (int o = 0; o < 5; ++o)
          e[o] = fma(ldvd<M>(Wins, (size_t)o * C_ + c), fs, e[o]);
      }
      double sq = 0.0;
#pragma unroll
      for (int o = 0; o < 5; ++o) {
        e[o] = e[o] + ldvd<M>(bins, o);
        sq = fma(e[o], e[o], sq);
        stv<M>(oute, (size_t)(b * OINS + o) * N_ + n, (float)e[o]);
      }
      size_t row = (size_t)b * N_ + n;
      float* qp = q32 + row * 8;
      qp[0] = (float)e[0]; qp[1] = (float)e[1]; qp[2] = (float)e[2];
      qp[3] = (float)e[3]; qp[4] = (float)e[4]; qp[5] = (float)sq;
      qp[6] = 0.f; qp[7] = 0.f;
      double* qd = q64 + row * 8;
      qd[0] = e[0]; qd[1] = e[1]; qd[2] = e[2]; qd[3] = e[3]; qd[4] = e[4];
      qd[5] = sq; qd[6] = 0.0; qd[7] = 0.0;
    }
    __syncthreads();
  }
}

// ---------------------------------------------------------------------------
// Exact select-RANK via ballot radix descend over 128 packed keys.
// ---------------------------------------------------------------------------
template <int RANK>
__device__ __forceinline__ void select_core(u64 k0, u64 k1, bool& w0o,
                                            bool& w1o, u32& Pout) {
  u32 d0 = (u32)(k0 >> 32), d1 = (u32)(k1 >> 32);
  bool a0 = true, a1 = true, w0 = false, w1 = false;
  int rank = RANK, asize = 128;
  u32 prefix = 0, fill = 0;
  bool done = false;
#pragma unroll 1
  for (int bit = 31; bit >= 0; --bit) {
    u32 bm = 1u << bit;
    bool z0 = a0 && ((d0 & bm) == 0u);
    bool z1 = a1 && ((d1 & bm) == 0u);
    int c = __popcll(__ballot(z0)) + __popcll(__ballot(z1));
    if (c >= rank) {
      a0 = z0; a1 = z1; asize = c;
    } else {
      rank -= c; w0 = w0 || z0; w1 = w1 || z1;
      a0 = a0 && ((d0 & bm) != 0u); a1 = a1 && ((d1 & bm) != 0u);
      asize -= c; prefix |= bm;
    }
    if (asize == rank) { fill = bm - 1u; done = true; break; }
  }
  if (!done) {  // distance word fully decided; tie-break on index bits
    u32 m0 = (u32)k0, m1 = (u32)k1;
#pragma unroll 1
    for (int bit = 11; bit >= 0; --bit) {
      u32 bm = 1u << bit;
      bool z0 = a0 && ((m0 & bm) == 0u);
      bool z1 = a1 && ((m1 & bm) == 0u);
      int c = __popcll(__ballot(z0)) + __popcll(__ballot(z1));
      if (c >= rank) {
        a0 = z0; a1 = z1; asize = c;
      } else {
        rank -= c; w0 = w0 || z0; w1 = w1 || z1;
        a0 = a0 && ((m0 & bm) != 0u); a1 = a1 && ((m1 & bm) != 0u);
        asize -= c;
      }
      if (asize == rank) break;
    }
  }
  w0o = w0 || a0;
  w1o = w1 || a1;
  Pout = prefix | fill;
}

__device__ __noinline__ float compress_row(u64* bufr, int lane) {
  u64 k0 = bufr[lane], k1 = bufr[lane + 64];
  bool w0, w1;
  u32 P;
  select_core<NSC>(k0, k1, w0, w1, P);
  u64 b0 = __ballot(w0), b1 = __ballot(w1);
  int o0 = mbcnt64(b0);
  int o1 = __popcll(b0) + mbcnt64(b1);
  bufr[lane] = ~0ull;
  bufr[lane + 64] = ~0ull;
  if (w0) bufr[o0] = k0;
  if (w1) bufr[o1] = k1;
  return (P >= 0xFF800000u) ? __builtin_inff() : unmonof(P);
}

__device__ __noinline__ void final_row(u64* bufr, int lane,
                                       u32* __restrict__ nnrow) {
  u64 k0 = bufr[lane], k1 = bufr[lane + 64];
  bool w0, w1;
  u32 P;
  select_core<NSC>(k0, k1, w0, w1, P);
  u64 b0 = __ballot(w0), b1 = __ballot(w1);
  int o0 = mbcnt64(b0);
  int o1 = __popcll(b0) + mbcnt64(b1);
  if (w0) nnrow[o0] = (u32)k0 & (N_ - 1);
  if (w1) nnrow[o1] = (u32)k1 & (N_ - 1);
}

// ---------------------------------------------------------------------------
// Streaming f32 top-48 screen. One wave = 8 rows; no block barriers in the
// candidate loop. Dtype-independent (reads only q32). Writes nn48[row][48].
// ---------------------------------------------------------------------------
__global__ __launch_bounds__(256) void k_knn(const float* __restrict__ q32,
                                             u32* __restrict__ nn48) {
  __shared__ u64 bufs[4][ROWS][128];  // 32KB
  int tid = threadIdx.x, wid = tid >> 6, lane = tid & 63;
  int gw = blockIdx.x * 4 + wid;  // 0..4095
  int b = gw >> 9;
  int r0 = (gw & 511) * ROWS;
  const float* qb = q32 + (((size_t)b) << 12) * 8;
  u64(*buf)[128] = bufs[wid];

#pragma unroll
  for (int i = 0; i < 2 * ROWS; ++i) bufs[wid][0][i * 64 + lane] = ~0ull;

  float er[ROWS][6], t[ROWS];
  int cnt[ROWS];
#pragma unroll
  for (int r = 0; r < ROWS; ++r) {
    const float* qr = qb + (size_t)(r0 + r) * 8;
    er[r][0] = qr[0]; er[r][1] = qr[1]; er[r][2] = qr[2];
    er[r][3] = qr[3]; er[r][4] = qr[4]; er[r][5] = qr[5];
    t[r] = __builtin_inff();
    cnt[r] = 0;
  }

#pragma unroll 1
  for (int g = 0; g < 64; ++g) {
    int m = g * 64 + lane;
    float4 A = *(const float4*)(qb + (size_t)m * 8);
    float4 Bv = *(const float4*)(qb + (size_t)m * 8 + 4);
#pragma unroll
    for (int r = 0; r < ROWS; ++r) {
      float dot = er[r][0] * A.x;
      dot = fmaf(er[r][1], A.y, dot);
      dot = fmaf(er[r][2], A.z, dot);
      dot = fmaf(er[r][3], A.w, dot);
      dot = fmaf(er[r][4], Bv.x, dot);
      float d = __fadd_rn(__fsub_rn(er[r][5], 2.0f * dot), Bv.y);
      bool pred = d <= t[r];
      u64 mk = __ballot(pred);
      if (mk) {  // wave-uniform
        u64 key = ((u64)monof(d) << 32) | (u32)m;
#pragma unroll
        for (int h = 0; h < 2; ++h) {  // 32-lane halves: bounded appends
          u64 hsel = (h == 0) ? 0x00000000FFFFFFFFull : 0xFFFFFFFF00000000ull;
          u64 hm = mk & hsel;
          int hc = __popcll(hm);
          if (hc) {
            if (cnt[r] + hc > 128) {
              t[r] = compress_row(&buf[r][0], lane);
              cnt[r] = NSC;
              pred = d <= t[r];
              mk = __ballot(pred);
              hm = mk & hsel;
              hc = __popcll(hm);
            }
            if (hc) {
              int off = mbcnt64(hm);
              bool inh = (h == 0) ? (lane < 32) : (lane >= 32);
              if (pred && inh) buf[r][cnt[r] + off] = key;
              cnt[r] += hc;
            }
          }
        }
      }
    }
  }
  u32* nnbase = nn48 + (size_t)(b * N_ + r0) * NSC;
#pragma unroll 1
  for (int r = 0; r < ROWS; ++r) final_row(&buf[r][0], lane, nnbase + r * NSC);
}

// ---------------------------------------------------------------------------
// Per-row (one wave each): f64 rescore of 48 -> top-30 set -> gather/max
// (float2/lane from f32 fT) -> W_sem projection (13x4 lanes, quad reduce).
// ---------------------------------------------------------------------------
template <int M>
__global__ __launch_bounds__(256) void k_out(
    const u32* flag, const double* __restrict__ q64,
    const u32* __restrict__ nn48, const void* fsem,
    const float* __restrict__ fT, int useFT, const void* Wsem,
    const void* bsem, void* outv) {
  if (*flag != (u32)M) return;
  __shared__ float wsm[13 * 132];
  __shared__ float bsm[16];
  __shared__ u32 idxw[4][32];
  __shared__ float fls[4][128];

  int tid = threadIdx.x, wid = tid >> 6, lane = tid & 63;
  for (int i = tid; i < 13 * 128; i += 256)
    wsm[(i >> 7) * 132 + (i & 127)] = ldv<M>(Wsem, i);
  if (tid < OSEM) bsm[tid] = ldv<M>(bsem, tid);
  __syncthreads();

  int row = blockIdx.x * 4 + wid;  // 0..32767
  int b = row >> 12, n = row & (N_ - 1);

  // --- f64 rescore of the 48 screened candidates ---
  const double* qdb = q64 + (((size_t)b) << 12) * 8;
  const double* qdr = q64 + (size_t)row * 8;
  double D0 = qdr[0], D1 = qdr[1], D2 = qdr[2], D3 = qdr[3], D4 = qdr[4],
         DS = qdr[5];
  u64 key = ~0ull;
  u32 myid = 0;
  if (lane < NSC) {
    myid = nn48[(size_t)row * NSC + lane];
    const double* qm = qdb + (size_t)myid * 8;
    double dot = D0 * qm[0];
    dot = fma(D1, qm[1], dot);
    dot = fma(D2, qm[2], dot);
    dot = fma(D3, qm[3], dot);
    dot = fma(D4, qm[4], dot);
    double d = (DS - 2.0 * dot) + qm[5];
    key = (monod(d) & ~0xFFFull) | myid;  // (dist, idx) lexicographic
  }
  int rank = 0;
#pragma unroll 8
  for (int j = 0; j < NSC; ++j) {
    u64 kj = shfl_u64(key, j);
    rank += (kj < key) ? 1 : 0;
  }
  if (lane < NSC && rank < KNN) idxw[wid][rank] = myid;
  __syncthreads();

  // --- gather/max: lane holds channels {2*lane, 2*lane+1} ---
  float mx0 = -__builtin_inff(), mx1 = -__builtin_inff();
  int c0 = lane * 2;
  if (useFT) {
    const float* fb = fT + (((size_t)b) << 12) * C_;
#pragma unroll 2
    for (int k = 0; k < KNN; ++k) {
      int id = (int)idxw[wid][k];
      float2 v = *(const float2*)(fb + (size_t)id * C_ + c0);
      mx0 = fmaxf(mx0, v.x);
      mx1 = fmaxf(mx1, v.y);
    }
  } else {
    size_t base = ((size_t)b * C_ + c0) * N_;
#pragma unroll 2
    for (int k = 0; k < KNN; ++k) {
      int id = (int)idxw[wid][k];
      mx0 = fmaxf(mx0, ldv<M>(fsem, base + id));
      mx1 = fmaxf(mx1, ldv<M>(fsem, base + N_ + id));
    }
  }
  fls[wid][c0] = mx0;
  fls[wid][c0 + 1] = mx1;
  __syncthreads();

  // --- projection: lanes (o<13, g<4), 32 channels each, quad shfl reduce ---
  if (lane < 52) {
    int o = lane >> 2, g = lane & 3;
    const float* wr = &wsm[o * 132 + g * 32];
    const float* fr = &fls[wid][g * 32];
    float s = 0.f;
#pragma unroll
    for (int c = 0; c < 32; ++c) s = fmaf(wr[c], fr[c], s);
    s += __shfl_xor(s, 1, 64);
    s += __shfl_xor(s, 2, 64);
    if (g == 0)
      stv<M>(outv, ((size_t)b * OSEM + o) * N_ + n, s + bsm[o]);
  }
}

// ---------------------------------------------------------------------------
extern "C" void kernel_launch(void* const* d_in, const int* in_sizes, int n_in,
                              void* d_out, int out_size, void* d_ws,
                              size_t ws_size, hipStream_t stream) {
  (void)in_sizes; (void)n_in; (void)out_size;
  const void* fsem = d_in[0];
  const void* fins = d_in[1];
  const void* Wad = d_in[2];
  const void* bad = d_in[3];
  const void* gad = d_in[4];
  const void* bead = d_in[5];
  const void* Wins = d_in[6];
  const void* bins = d_in[7];
  const void* Wsem = d_in[8];
  const void* bsem = d_in[9];

  char* ws = (char*)d_ws;
  u32* flag = (u32*)ws;                     // @0
  float* q32 = (float*)(ws + (1 << 20));    // @1MB, 1MB
  double* q64 = (double*)(ws + (2 << 20));  // @2MB, 2MB
  u32* nn48 = (u32*)(ws + (4 << 20));       // @4MB, 6MB
  float* fT = (float*)(ws + (10 << 20));    // @10MB, 16MB
  int useFT = (ws_size >= (size_t)(26 << 20)) ? 1 : 0;

  void* oute_bf = (void*)((u16*)d_out + (size_t)B_ * OSEM * N_);
  void* oute_f32 = (void*)((float*)d_out + (size_t)B_ * OSEM * N_);

  k_sniff<<<1, 64, 0, stream>>>(fsem, flag);

  if (useFT) {
    k_transpose<u16, 0><<<dim3(64, 2, 8), 256, 0, stream>>>(flag, fsem, fT);
    k_transpose<float, 1><<<dim3(64, 2, 8), 256, 0, stream>>>(flag, fsem, fT);
  }
  k_fused<0><<<dim3(32, 8), 256, 0, stream>>>(flag, fsem, fins, Wad, bad, gad,
                                              bead, Wins, bins, q32, q64,
                                              oute_bf);
  k_fused<1><<<dim3(32, 8), 256, 0, stream>>>(flag, fsem, fins, Wad, bad, gad,
                                              bead, Wins, bins, q32, q64,
                                              oute_f32);
  k_knn<<<dim3(1024), 256, 0, stream>>>(q32, nn48);
  k_out<0><<<dim3(8192), 256, 0, stream>>>(flag, q64, nn48, fsem, fT, useFT,
                                           Wsem, bsem, d_out);
  k_out<1><<<dim3(8192), 256, 0, stream>>>(flag, q64, nn48, fsem, fT, useFT,
                                           Wsem, bsem, d_out);
}

// Round 7
// 520.845 us; speedup vs baseline: 6.6073x; 1.1875x over previous
//
#include <hip/hip_runtime.h>
#include <stdint.h>

#define B_ 8
#define N_ 4096
#define C_ 128
#define OSEM 13
#define OINS 5
#define KNN 30
#define NSC 48   // f32-screened candidates, rescored in f64
#define ROWS 4   // rows per wave in k_knn

typedef unsigned short u16;
typedef unsigned int u32;
typedef unsigned long long u64;

__device__ __forceinline__ float bf2f(u16 v) {
  u32 u = ((u32)v) << 16;
  return __uint_as_float(u);
}
__device__ __forceinline__ u16 f2bf(float f) {
  u32 u = __float_as_uint(f);
  u32 r = (u + 0x7FFFu + ((u >> 16) & 1u)) >> 16;  // RNE
  return (u16)r;
}
__device__ __forceinline__ u32 monof(float d) {
  u32 u = __float_as_uint(d);
  return (u & 0x80000000u) ? ~u : (u | 0x80000000u);
}
__device__ __forceinline__ float unmonof(u32 p) {
  u32 u = (p & 0x80000000u) ? (p & 0x7FFFFFFFu) : ~p;
  return __uint_as_float(u);
}
__device__ __forceinline__ u64 monod(double d) {
  u64 u = (u64)__double_as_longlong(d);
  return (u & 0x8000000000000000ull) ? ~u : (u | 0x8000000000000000ull);
}
__device__ __forceinline__ int mbcnt64(u64 m) {
  return __builtin_amdgcn_mbcnt_hi((u32)(m >> 32),
                                   __builtin_amdgcn_mbcnt_lo((u32)m, 0));
}
__device__ __forceinline__ u64 shfl_u64(u64 v, int src) {
  u32 lo = (u32)__shfl((int)(u32)v, src, 64);
  u32 hi = (u32)__shfl((int)(u32)(v >> 32), src, 64);
  return ((u64)hi << 32) | lo;
}

template <int M>
__device__ __forceinline__ float ldv(const void* p, size_t i) {
  if (M == 0) return bf2f(((const u16*)p)[i]);
  return ((const float*)p)[i];
}
template <int M>
__device__ __forceinline__ double ldvd(const void* p, size_t i) {
  return (double)ldv<M>(p, i);
}
template <int M>
__device__ __forceinline__ void stv(void* p, size_t i, float v) {
  if (M == 0) ((u16*)p)[i] = f2bf(v);
  else ((float*)p)[i] = v;
}
template <int M>
__device__ __forceinline__ void ld8(const void* p, size_t i, float* o) {
  if (M == 0) {
    uint4 u = *(const uint4*)((const u16*)p + i);
    o[0] = __uint_as_float(u.x << 16); o[1] = __uint_as_float(u.x & 0xFFFF0000u);
    o[2] = __uint_as_float(u.y << 16); o[3] = __uint_as_float(u.y & 0xFFFF0000u);
    o[4] = __uint_as_float(u.z << 16); o[5] = __uint_as_float(u.z & 0xFFFF0000u);
    o[6] = __uint_as_float(u.w << 16); o[7] = __uint_as_float(u.w & 0xFFFF0000u);
  } else {
    const float4* f = (const float4*)((const float*)p + i);
    float4 a = f[0], b = f[1];
    o[0] = a.x; o[1] = a.y; o[2] = a.z; o[3] = a.w;
    o[4] = b.x; o[5] = b.y; o[6] = b.z; o[7] = b.w;
  }
}

// ---------------------------------------------------------------------------
// Sniff dtype from data (0=bf16, 1=fp32).
// ---------------------------------------------------------------------------
__global__ void k_sniff(const void* fsem, u32* flag) {
  __shared__ int s[64];
  int lane = threadIdx.x;
  const u16* p = (const u16*)fsem;
  int cnt = 0;
#pragma unroll 8
  for (int i = 0; i < 64; ++i) {
    u16 v = p[2 * (lane * 64 + i)];
    u32 e = (v >> 7) & 0xFF;
    cnt += (e >= 0x60 && e <= 0x9F) ? 1 : 0;
  }
  s[lane] = cnt;
  __syncthreads();
  if (lane == 0) {
    int t = 0;
    for (int i = 0; i < 64; ++i) t += s[i];
    flag[0] = (t >= 2458) ? 0u : 1u;  // bf16 ~4096, fp32 ~1024
  }
}

// ---------------------------------------------------------------------------
// Transpose f_sem[b][c][n] -> fT[b][n][c] as FLOAT for coalesced gathers.
// ---------------------------------------------------------------------------
template <typename T, int M>
__global__ __launch_bounds__(256) void k_transpose(const u32* flag,
                                                   const void* src_,
                                                   float* __restrict__ dst) {
  if (*flag != (u32)M) return;
  __shared__ float t[64][65];
  const T* src0 = (const T*)src_;
  int b = blockIdx.z, c0 = blockIdx.y * 64, n0 = blockIdx.x * 64;
  int tid = threadIdx.x, j = tid & 63, i0 = tid >> 6;
  const T* src = src0 + (size_t)(b * C_ + c0) * N_ + n0;
#pragma unroll
  for (int k = 0; k < 16; ++k) {
    int i = k * 4 + i0;
    t[i][j] = ldv<M>(src, (size_t)i * N_ + j);
  }
  __syncthreads();
  float* d = dst + ((size_t)b * N_ + n0) * C_ + c0;
#pragma unroll
  for (int k = 0; k < 16; ++k) {
    int nl = k * 4 + i0;
    d[(size_t)nl * C_ + j] = t[j][nl];
  }
}

// ---------------------------------------------------------------------------
// Fused (ALL f64, verified round 5): adapted = W_adapt@f_sem ; relu affine ;
// fs = f_ins + h ; e = W_ins@fs ; sq. Emits e_ins + q32 + q64 records.
// ---------------------------------------------------------------------------
template <int M>
__global__ __launch_bounds__(256) void k_fused(
    const u32* flag, const void* fsem, const void* fins, const void* Wad,
    const void* bad, const void* gad, const void* bead, const void* Wins,
    const void* bins, float* __restrict__ q32, double* __restrict__ q64,
    void* oute) {
  if (*flag != (u32)M) return;
  __shared__ __align__(16) char smem[65536];
  double* xs = (double*)smem;            // [32][128] f64 (32KB)
  double* wt = (double*)(smem + 32768);  // [32][128] f64 (32KB)
  float* fsh = (float*)smem;             // phase 2: [128][64] hi (32KB)
  float* fsl = (float*)(smem + 32768);   // phase 2: [128][64] lo (32KB)

  int tid = threadIdx.x, tx = tid & 15, ty = tid >> 4;
  int b = blockIdx.y, n0 = blockIdx.x * 128;

  double acc[8][8];
#pragma unroll
  for (int i = 0; i < 8; ++i)
#pragma unroll
    for (int j = 0; j < 8; ++j) acc[i][j] = 0.0;

  for (int kk = 0; kk < 128; kk += 32) {
    __syncthreads();
#pragma unroll
    for (int it = 0; it < 2; ++it) {
      int g = it * 256 + tid;
      int r = g >> 4, c8 = g & 15;
      float v[8];
      ld8<M>(fsem, (size_t)(b * C_ + kk + r) * N_ + n0 + c8 * 8, v);
#pragma unroll
      for (int j = 0; j < 8; ++j) xs[r * 128 + c8 * 8 + j] = (double)v[j];
    }
#pragma unroll
    for (int it = 0; it < 16; ++it) {
      int f = it * 256 + tid;
      int k = f >> 7, c = f & 127;
      wt[k * 128 + c] = ldvd<M>(Wad, (size_t)c * C_ + kk + k);
    }
    __syncthreads();
#pragma unroll 2
    for (int k = 0; k < 32; ++k) {
      double xv[8], wv[8];
#pragma unroll
      for (int j = 0; j < 8; ++j) xv[j] = xs[k * 128 + tx * 8 + j];
#pragma unroll
      for (int i = 0; i < 8; ++i) wv[i] = wt[k * 128 + ty * 8 + i];
#pragma unroll
      for (int i = 0; i < 8; ++i)
#pragma unroll
        for (int j = 0; j < 8; ++j) acc[i][j] = fma(wv[i], xv[j], acc[i][j]);
    }
  }

#pragma unroll
  for (int i = 0; i < 8; ++i) {
    int c = ty * 8 + i;
    double ba = ldvd<M>(bad, c), ga = ldvd<M>(gad, c), be = ldvd<M>(bead, c);
    float ff[8];
    ld8<M>(fins, (size_t)(b * C_ + c) * N_ + n0 + tx * 8, ff);
#pragma unroll
    for (int j = 0; j < 8; ++j) {
      double a = acc[i][j] + ba;
      double h = a * ga + be;
      h = h > 0.0 ? h : 0.0;
      acc[i][j] = (double)ff[j] + h;
    }
  }
  __syncthreads();

#pragma unroll 1
  for (int p = 0; p < 2; ++p) {
    if ((tx >> 3) == p) {
      int nq = tx * 8 - p * 64;
#pragma unroll
      for (int i = 0; i < 8; ++i) {
        int c = ty * 8 + i;
#pragma unroll
        for (int j = 0; j < 8; ++j) {
          double fs = acc[i][j];
          float hi = (float)fs;
          fsh[c * 64 + nq + j] = hi;
          fsl[c * 64 + nq + j] = (float)(fs - (double)hi);
        }
      }
    }
    __syncthreads();
    if (tid < 64) {
      int n = n0 + p * 64 + tid;
      double e[5] = {0.0, 0.0, 0.0, 0.0, 0.0};
#pragma unroll 4
      for (int c = 0; c < 128; ++c) {
        double fs = (double)fsh[c * 64 + tid] + (double)fsl[c * 64 + tid];
#pragma unroll
        for (int o = 0; o < 5; ++o)
          e[o] = fma(ldvd<M>(Wins, (size_t)o * C_ + c), fs, e[o]);
      }
      double sq = 0.0;
#pragma unroll
      for (int o = 0; o < 5; ++o) {
        e[o] = e[o] + ldvd<M>(bins, o);
        sq = fma(e[o], e[o], sq);
        stv<M>(oute, (size_t)(b * OINS + o) * N_ + n, (float)e[o]);
      }
      size_t row = (size_t)b * N_ + n;
      float* qp = q32 + row * 8;
      qp[0] = (float)e[0]; qp[1] = (float)e[1]; qp[2] = (float)e[2];
      qp[3] = (float)e[3]; qp[4] = (float)e[4]; qp[5] = (float)sq;
      qp[6] = 0.f; qp[7] = 0.f;
      double* qd = q64 + row * 8;
      qd[0] = e[0]; qd[1] = e[1]; qd[2] = e[2]; qd[3] = e[3]; qd[4] = e[4];
      qd[5] = sq; qd[6] = 0.0; qd[7] = 0.0;
    }
    __syncthreads();
  }
}

// ---------------------------------------------------------------------------
// Exact select-RANK via ballot radix descend over 128 packed keys.
// ---------------------------------------------------------------------------
template <int RANK>
__device__ __forceinline__ void select_core(u64 k0, u64 k1, bool& w0o,
                                            bool& w1o, u32& Pout) {
  u32 d0 = (u32)(k0 >> 32), d1 = (u32)(k1 >> 32);
  bool a0 = true, a1 = true, w0 = false, w1 = false;
  int rank = RANK, asize = 128;
  u32 prefix = 0, fill = 0;
  bool done = false;
#pragma unroll 1
  for (int bit = 31; bit >= 0; --bit) {
    u32 bm = 1u << bit;
    bool z0 = a0 && ((d0 & bm) == 0u);
    bool z1 = a1 && ((d1 & bm) == 0u);
    int c = __popcll(__ballot(z0)) + __popcll(__ballot(z1));
    if (c >= rank) {
      a0 = z0; a1 = z1; asize = c;
    } else {
      rank -= c; w0 = w0 || z0; w1 = w1 || z1;
      a0 = a0 && ((d0 & bm) != 0u); a1 = a1 && ((d1 & bm) != 0u);
      asize -= c; prefix |= bm;
    }
    if (asize == rank) { fill = bm - 1u; done = true; break; }
  }
  if (!done) {  // distance word fully decided; tie-break on index bits
    u32 m0 = (u32)k0, m1 = (u32)k1;
#pragma unroll 1
    for (int bit = 11; bit >= 0; --bit) {
      u32 bm = 1u << bit;
      bool z0 = a0 && ((m0 & bm) == 0u);
      bool z1 = a1 && ((m1 & bm) == 0u);
      int c = __popcll(__ballot(z0)) + __popcll(__ballot(z1));
      if (c >= rank) {
        a0 = z0; a1 = z1; asize = c;
      } else {
        rank -= c; w0 = w0 || z0; w1 = w1 || z1;
        a0 = a0 && ((m0 & bm) != 0u); a1 = a1 && ((m1 & bm) != 0u);
        asize -= c;
      }
      if (asize == rank) break;
    }
  }
  w0o = w0 || a0;
  w1o = w1 || a1;
  Pout = prefix | fill;
}

__device__ __noinline__ float compress_row(u64* bufr, int lane) {
  u64 k0 = bufr[lane], k1 = bufr[lane + 64];
  bool w0, w1;
  u32 P;
  select_core<NSC>(k0, k1, w0, w1, P);
  u64 b0 = __ballot(w0), b1 = __ballot(w1);
  int o0 = mbcnt64(b0);
  int o1 = __popcll(b0) + mbcnt64(b1);
  bufr[lane] = ~0ull;
  bufr[lane + 64] = ~0ull;
  if (w0) bufr[o0] = k0;
  if (w1) bufr[o1] = k1;
  return (P >= 0xFF800000u) ? __builtin_inff() : unmonof(P);
}

__device__ __noinline__ void final_row(u64* bufr, int lane,
                                       u32* __restrict__ nnrow) {
  u64 k0 = bufr[lane], k1 = bufr[lane + 64];
  bool w0, w1;
  u32 P;
  select_core<NSC>(k0, k1, w0, w1, P);
  u64 b0 = __ballot(w0), b1 = __ballot(w1);
  int o0 = mbcnt64(b0);
  int o1 = __popcll(b0) + mbcnt64(b1);
  if (w0) nnrow[o0] = (u32)k0 & (N_ - 1);
  if (w1) nnrow[o1] = (u32)k1 & (N_ - 1);
}

// ---------------------------------------------------------------------------
// Streaming f32 top-48 screen. One wave = 4 rows; no block barriers in the
// candidate loop. Screen rank value d' = sq_m - 2*dot (ordering-equivalent
// to d per row; exactness restored by f64 rescore of the 48 in k_out).
// ---------------------------------------------------------------------------
__global__ __launch_bounds__(256) void k_knn(const float* __restrict__ q32,
                                             u32* __restrict__ nn48) {
  __shared__ u64 bufs[4][ROWS][128];  // 16KB
  int tid = threadIdx.x, wid = tid >> 6, lane = tid & 63;
  int gw = blockIdx.x * 4 + wid;  // 0..8191
  int b = gw >> 10;               // 1024 waves per batch
  int r0 = (gw & 1023) * ROWS;
  const float* qb = q32 + (((size_t)b) << 12) * 8;
  u64(*buf)[128] = bufs[wid];

#pragma unroll
  for (int i = 0; i < 2 * ROWS; ++i) bufs[wid][0][i * 64 + lane] = ~0ull;

  float er[ROWS][5], t[ROWS];
  int cnt[ROWS];
#pragma unroll
  for (int r = 0; r < ROWS; ++r) {
    const float* qr = qb + (size_t)(r0 + r) * 8;
    er[r][0] = qr[0]; er[r][1] = qr[1]; er[r][2] = qr[2];
    er[r][3] = qr[3]; er[r][4] = qr[4];
    t[r] = __builtin_inff();
    cnt[r] = 0;
  }

#pragma unroll 1
  for (int g = 0; g < 64; ++g) {
    int m = g * 64 + lane;
    float4 A = *(const float4*)(qb + (size_t)m * 8);
    float2 Bv = *(const float2*)(qb + (size_t)m * 8 + 4);
#pragma unroll
    for (int r = 0; r < ROWS; ++r) {
      float dot = er[r][0] * A.x;
      dot = fmaf(er[r][1], A.y, dot);
      dot = fmaf(er[r][2], A.z, dot);
      dot = fmaf(er[r][3], A.w, dot);
      dot = fmaf(er[r][4], Bv.x, dot);
      float d = fmaf(-2.f, dot, Bv.y);  // screen rank value
      bool pred = d <= t[r];
      u64 mk = __ballot(pred);
      if (mk) {  // wave-uniform
        u64 key = ((u64)monof(d) << 32) | (u32)m;
        int hc = __popcll(mk);
        if (cnt[r] + hc > 128) {
          t[r] = compress_row(&buf[r][0], lane);
          cnt[r] = NSC;
          pred = d <= t[r];
          mk = __ballot(pred);
          hc = __popcll(mk);
        }
        if (hc) {
          int off = mbcnt64(mk);
          if (pred) buf[r][cnt[r] + off] = key;
          cnt[r] += hc;
        }
      }
    }
  }
  u32* nnbase = nn48 + (size_t)(b * N_ + r0) * NSC;
#pragma unroll 1
  for (int r = 0; r < ROWS; ++r) final_row(&buf[r][0], lane, nnbase + r * NSC);
}

// ---------------------------------------------------------------------------
// Per-row (one wave each): f64 rescore of 48 -> top-30 set -> gather/max
// (float2/lane from f32 fT) -> W_sem projection (13x4 lanes, quad reduce).
// ---------------------------------------------------------------------------
template <int M>
__global__ __launch_bounds__(256) void k_out(
    const u32* flag, const double* __restrict__ q64,
    const u32* __restrict__ nn48, const void* fsem,
    const float* __restrict__ fT, int useFT, const void* Wsem,
    const void* bsem, void* outv) {
  if (*flag != (u32)M) return;
  __shared__ float wsm[13 * 132];
  __shared__ float bsm[16];
  __shared__ u32 idxw[4][32];
  __shared__ float fls[4][128];

  int tid = threadIdx.x, wid = tid >> 6, lane = tid & 63;
  for (int i = tid; i < 13 * 128; i += 256)
    wsm[(i >> 7) * 132 + (i & 127)] = ldv<M>(Wsem, i);
  if (tid < OSEM) bsm[tid] = ldv<M>(bsem, tid);
  __syncthreads();

  int row = blockIdx.x * 4 + wid;  // 0..32767
  int b = row >> 12, n = row & (N_ - 1);

  // --- f64 rescore of the 48 screened candidates ---
  const double* qdb = q64 + (((size_t)b) << 12) * 8;
  const double* qdr = q64 + (size_t)row * 8;
  double D0 = qdr[0], D1 = qdr[1], D2 = qdr[2], D3 = qdr[3], D4 = qdr[4],
         DS = qdr[5];
  u64 key = ~0ull;
  u32 myid = 0;
  if (lane < NSC) {
    myid = nn48[(size_t)row * NSC + lane];
    const double* qm = qdb + (size_t)myid * 8;
    double dot = D0 * qm[0];
    dot = fma(D1, qm[1], dot);
    dot = fma(D2, qm[2], dot);
    dot = fma(D3, qm[3], dot);
    dot = fma(D4, qm[4], dot);
    double d = (DS - 2.0 * dot) + qm[5];
    key = (monod(d) & ~0xFFFull) | myid;  // (dist, idx) lexicographic
  }
  int rank = 0;
#pragma unroll 8
  for (int j = 0; j < NSC; ++j) {
    u64 kj = shfl_u64(key, j);
    rank += (kj < key) ? 1 : 0;
  }
  if (lane < NSC && rank < KNN) idxw[wid][rank] = myid;
  __syncthreads();

  // --- gather/max: lane holds channels {2*lane, 2*lane+1} ---
  float mx0 = -__builtin_inff(), mx1 = -__builtin_inff();
  int c0 = lane * 2;
  if (useFT) {
    const float* fb = fT + (((size_t)b) << 12) * C_;
#pragma unroll 2
    for (int k = 0; k < KNN; ++k) {
      int id = (int)idxw[wid][k];
      float2 v = *(const float2*)(fb + (size_t)id * C_ + c0);
      mx0 = fmaxf(mx0, v.x);
      mx1 = fmaxf(mx1, v.y);
    }
  } else {
    size_t base = ((size_t)b * C_ + c0) * N_;
#pragma unroll 2
    for (int k = 0; k < KNN; ++k) {
      int id = (int)idxw[wid][k];
      mx0 = fmaxf(mx0, ldv<M>(fsem, base + id));
      mx1 = fmaxf(mx1, ldv<M>(fsem, base + N_ + id));
    }
  }
  fls[wid][c0] = mx0;
  fls[wid][c0 + 1] = mx1;
  __syncthreads();

  // --- projection: lanes (o<13, g<4), 32 channels each, quad shfl reduce ---
  if (lane < 52) {
    int o = lane >> 2, g = lane & 3;
    const float* wr = &wsm[o * 132 + g * 32];
    const float* fr = &fls[wid][g * 32];
    float s = 0.f;
#pragma unroll
    for (int c = 0; c < 32; ++c) s = fmaf(wr[c], fr[c], s);
    s += __shfl_xor(s, 1, 64);
    s += __shfl_xor(s, 2, 64);
    if (g == 0)
      stv<M>(outv, ((size_t)b * OSEM + o) * N_ + n, s + bsm[o]);
  }
}

// ---------------------------------------------------------------------------
extern "C" void kernel_launch(void* const* d_in, const int* in_sizes, int n_in,
                              void* d_out, int out_size, void* d_ws,
                              size_t ws_size, hipStream_t stream) {
  (void)in_sizes; (void)n_in; (void)out_size;
  const void* fsem = d_in[0];
  const void* fins = d_in[1];
  const void* Wad = d_in[2];
  const void* bad = d_in[3];
  const void* gad = d_in[4];
  const void* bead = d_in[5];
  const void* Wins = d_in[6];
  const void* bins = d_in[7];
  const void* Wsem = d_in[8];
  const void* bsem = d_in[9];

  char* ws = (char*)d_ws;
  u32* flag = (u32*)ws;                     // @0
  float* q32 = (float*)(ws + (1 << 20));    // @1MB, 1MB
  double* q64 = (double*)(ws + (2 << 20));  // @2MB, 2MB
  u32* nn48 = (u32*)(ws + (4 << 20));       // @4MB, 6MB
  float* fT = (float*)(ws + (10 << 20));    // @10MB, 16MB
  int useFT = (ws_size >= (size_t)(26 << 20)) ? 1 : 0;

  void* oute_bf = (void*)((u16*)d_out + (size_t)B_ * OSEM * N_);
  void* oute_f32 = (void*)((float*)d_out + (size_t)B_ * OSEM * N_);

  k_sniff<<<1, 64, 0, stream>>>(fsem, flag);

  if (useFT) {
    k_transpose<u16, 0><<<dim3(64, 2, 8), 256, 0, stream>>>(flag, fsem, fT);
    k_transpose<float, 1><<<dim3(64, 2, 8), 256, 0, stream>>>(flag, fsem, fT);
  }
  k_fused<0><<<dim3(32, 8), 256, 0, stream>>>(flag, fsem, fins, Wad, bad, gad,
                                              bead, Wins, bins, q32, q64,
                                              oute_bf);
  k_fused<1><<<dim3(32, 8), 256, 0, stream>>>(flag, fsem, fins, Wad, bad, gad,
                                              bead, Wins, bins, q32, q64,
                                              oute_f32);
  k_knn<<<dim3(2048), 256, 0, stream>>>(q32, nn48);
  k_out<0><<<dim3(8192), 256, 0, stream>>>(flag, q64, nn48, fsem, fT, useFT,
                                           Wsem, bsem, d_out);
  k_out<1><<<dim3(8192), 256, 0, stream>>>(flag, q64, nn48, fsem, fT, useFT,
                                           Wsem, bsem, d_out);
}

// Round 8
// 481.245 us; speedup vs baseline: 7.1510x; 1.0823x over previous
//
#include <hip/hip_runtime.h>
#include <stdint.h>

#define B_ 8
#define N_ 4096
#define C_ 128
#define OSEM 13
#define OINS 5
#define KNN 30
#define NSC 48   // f32-screened candidates, rescored in f64
#define ROWS 4   // rows per wave in k_knn

typedef unsigned short u16;
typedef unsigned int u32;
typedef unsigned long long u64;

__device__ __forceinline__ float bf2f(u16 v) {
  u32 u = ((u32)v) << 16;
  return __uint_as_float(u);
}
__device__ __forceinline__ u16 f2bf(float f) {
  u32 u = __float_as_uint(f);
  u32 r = (u + 0x7FFFu + ((u >> 16) & 1u)) >> 16;  // RNE
  return (u16)r;
}
__device__ __forceinline__ u32 monof(float d) {
  u32 u = __float_as_uint(d);
  return (u & 0x80000000u) ? ~u : (u | 0x80000000u);
}
__device__ __forceinline__ float unmonof(u32 p) {
  u32 u = (p & 0x80000000u) ? (p & 0x7FFFFFFFu) : ~p;
  return __uint_as_float(u);
}
__device__ __forceinline__ u64 monod(double d) {
  u64 u = (u64)__double_as_longlong(d);
  return (u & 0x8000000000000000ull) ? ~u : (u | 0x8000000000000000ull);
}
__device__ __forceinline__ int mbcnt64(u64 m) {
  return __builtin_amdgcn_mbcnt_hi((u32)(m >> 32),
                                   __builtin_amdgcn_mbcnt_lo((u32)m, 0));
}
__device__ __forceinline__ u64 shfl_u64(u64 v, int src) {
  u32 lo = (u32)__shfl((int)(u32)v, src, 64);
  u32 hi = (u32)__shfl((int)(u32)(v >> 32), src, 64);
  return ((u64)hi << 32) | lo;
}

template <int M>
__device__ __forceinline__ float ldv(const void* p, size_t i) {
  if (M == 0) return bf2f(((const u16*)p)[i]);
  return ((const float*)p)[i];
}
template <int M>
__device__ __forceinline__ double ldvd(const void* p, size_t i) {
  return (double)ldv<M>(p, i);
}
template <int M>
__device__ __forceinline__ void stv(void* p, size_t i, float v) {
  if (M == 0) ((u16*)p)[i] = f2bf(v);
  else ((float*)p)[i] = v;
}
template <int M>
__device__ __forceinline__ void ld8(const void* p, size_t i, float* o) {
  if (M == 0) {
    uint4 u = *(const uint4*)((const u16*)p + i);
    o[0] = __uint_as_float(u.x << 16); o[1] = __uint_as_float(u.x & 0xFFFF0000u);
    o[2] = __uint_as_float(u.y << 16); o[3] = __uint_as_float(u.y & 0xFFFF0000u);
    o[4] = __uint_as_float(u.z << 16); o[5] = __uint_as_float(u.z & 0xFFFF0000u);
    o[6] = __uint_as_float(u.w << 16); o[7] = __uint_as_float(u.w & 0xFFFF0000u);
  } else {
    const float4* f = (const float4*)((const float*)p + i);
    float4 a = f[0], b = f[1];
    o[0] = a.x; o[1] = a.y; o[2] = a.z; o[3] = a.w;
    o[4] = b.x; o[5] = b.y; o[6] = b.z; o[7] = b.w;
  }
}

// ---------------------------------------------------------------------------
// Sniff dtype from data (0=bf16, 1=fp32).
// ---------------------------------------------------------------------------
__global__ void k_sniff(const void* fsem, u32* flag) {
  __shared__ int s[64];
  int lane = threadIdx.x;
  const u16* p = (const u16*)fsem;
  int cnt = 0;
#pragma unroll 8
  for (int i = 0; i < 64; ++i) {
    u16 v = p[2 * (lane * 64 + i)];
    u32 e = (v >> 7) & 0xFF;
    cnt += (e >= 0x60 && e <= 0x9F) ? 1 : 0;
  }
  s[lane] = cnt;
  __syncthreads();
  if (lane == 0) {
    int t = 0;
    for (int i = 0; i < 64; ++i) t += s[i];
    flag[0] = (t >= 2458) ? 0u : 1u;  // bf16 ~4096, fp32 ~1024
  }
}

// ---------------------------------------------------------------------------
// Transpose f_sem[b][c][n] -> fT[b][n][c] in NATIVE dtype (bf16: 8MB, f32:16MB)
// ---------------------------------------------------------------------------
template <typename T>
__device__ __forceinline__ void transpose_body(const void* src_, void* dst_,
                                               char* tsm) {
  T* t = (T*)tsm;  // [64][65]
  const T* src0 = (const T*)src_;
  T* dst0 = (T*)dst_;
  int b = blockIdx.z, c0 = blockIdx.y * 64, n0 = blockIdx.x * 64;
  int tid = threadIdx.x, j = tid & 63, i0 = tid >> 6;
  const T* src = src0 + (size_t)(b * C_ + c0) * N_ + n0;
#pragma unroll
  for (int k = 0; k < 16; ++k) {
    int i = k * 4 + i0;
    t[i * 65 + j] = src[(size_t)i * N_ + j];
  }
  __syncthreads();
  T* dst = dst0 + ((size_t)b * N_ + n0) * C_ + c0;
#pragma unroll
  for (int k = 0; k < 16; ++k) {
    int nl = k * 4 + i0;
    dst[(size_t)nl * C_ + j] = t[j * 65 + nl];
  }
}

__global__ __launch_bounds__(256) void k_transpose(const u32* flag,
                                                   const void* src, void* dst,
                                                   int useFT0, int useFT1) {
  __shared__ __align__(16) char tsm[64 * 65 * 4];
  u32 f = *flag;
  if (f == 0) {
    if (!useFT0) return;
    transpose_body<u16>(src, dst, tsm);
  } else {
    if (!useFT1) return;
    transpose_body<float>(src, dst, tsm);
  }
}

// ---------------------------------------------------------------------------
// Fused (ALL f64, verified): adapted = W_adapt@f_sem ; relu affine ;
// fs = f_ins + h ; e = W_ins@fs ; sq. Emits e_ins + q32 + q64 records.
// Tile: 64 n-cols x 128 c. 512 blocks (2/CU). acc[4][8] f64 per thread.
// ---------------------------------------------------------------------------
template <int M>
__device__ void fused_body(const void* fsem, const void* fins, const void* Wad,
                           const void* bad, const void* gad, const void* bead,
                           const void* Wins, const void* bins,
                           float* __restrict__ q32, double* __restrict__ q64,
                           void* oute, char* smem) {
  double* xs = (double*)smem;            // [32][8 grp][10] f64 (20KB, padded)
  double* wt = (double*)(smem + 20480);  // [32][128] f64 (32KB)
  float* fsh = (float*)smem;             // phase 2: [128][64] hi (32KB)
  float* fsl = (float*)(smem + 32768);   // phase 2: [128][64] lo (32KB)

  int tid = threadIdx.x, tx = tid & 7, ty = tid >> 3;  // tx: n-grp, ty: c-grp
  int b = blockIdx.y, n0 = blockIdx.x * 64;

  double acc[4][8];
#pragma unroll
  for (int i = 0; i < 4; ++i)
#pragma unroll
    for (int j = 0; j < 8; ++j) acc[i][j] = 0.0;

  for (int kk = 0; kk < 128; kk += 32) {
    __syncthreads();
    {  // stage x chunk: 32 k-rows x 64 n-cols (thread: r=tid>>3, c8=tid&7)
      int r = tid >> 3, c8 = tid & 7;
      float v[8];
      ld8<M>(fsem, (size_t)(b * C_ + kk + r) * N_ + n0 + c8 * 8, v);
#pragma unroll
      for (int j = 0; j < 8; ++j) xs[r * 80 + c8 * 10 + j] = (double)v[j];
    }
#pragma unroll
    for (int it = 0; it < 16; ++it) {  // stage W^T chunk
      int f = it * 256 + tid;
      int k = f >> 7, c = f & 127;
      wt[k * 128 + c] = ldvd<M>(Wad, (size_t)c * C_ + kk + k);
    }
    __syncthreads();
#pragma unroll 2
    for (int k = 0; k < 32; ++k) {
      double xv[8], wv[4];
#pragma unroll
      for (int j = 0; j < 8; ++j) xv[j] = xs[k * 80 + tx * 10 + j];
#pragma unroll
      for (int i = 0; i < 4; ++i) wv[i] = wt[k * 128 + ty * 4 + i];
#pragma unroll
      for (int i = 0; i < 4; ++i)
#pragma unroll
        for (int j = 0; j < 8; ++j) acc[i][j] = fma(wv[i], xv[j], acc[i][j]);
    }
  }

  // epilogue: affine/relu/add (f64, np-faithful at f64 fidelity)
#pragma unroll
  for (int i = 0; i < 4; ++i) {
    int c = ty * 4 + i;
    double ba = ldvd<M>(bad, c), ga = ldvd<M>(gad, c), be = ldvd<M>(bead, c);
    float ff[8];
    ld8<M>(fins, (size_t)(b * C_ + c) * N_ + n0 + tx * 8, ff);
#pragma unroll
    for (int j = 0; j < 8; ++j) {
      double a = acc[i][j] + ba;
      double h = a * ga + be;
      h = h > 0.0 ? h : 0.0;
      acc[i][j] = (double)ff[j] + h;
    }
  }
  __syncthreads();  // GEMM LDS reads done; reuse as fsh/fsl

#pragma unroll
  for (int i = 0; i < 4; ++i) {
    int c = ty * 4 + i;
#pragma unroll
    for (int j = 0; j < 8; ++j) {
      double fs = acc[i][j];
      float hi = (float)fs;
      fsh[c * 64 + tx * 8 + j] = hi;
      fsl[c * 64 + tx * 8 + j] = (float)(fs - (double)hi);
    }
  }
  __syncthreads();
  if (tid < 64) {
    int n = n0 + tid;
    double e[5] = {0.0, 0.0, 0.0, 0.0, 0.0};
#pragma unroll 4
    for (int c = 0; c < 128; ++c) {
      double fs = (double)fsh[c * 64 + tid] + (double)fsl[c * 64 + tid];
#pragma unroll
      for (int o = 0; o < 5; ++o)
        e[o] = fma(ldvd<M>(Wins, (size_t)o * C_ + c), fs, e[o]);
    }
    double sq = 0.0;
#pragma unroll
    for (int o = 0; o < 5; ++o) {
      e[o] = e[o] + ldvd<M>(bins, o);
      sq = fma(e[o], e[o], sq);
      stv<M>(oute, (size_t)(b * OINS + o) * N_ + n, (float)e[o]);
    }
    size_t row = (size_t)b * N_ + n;
    float* qp = q32 + row * 8;
    qp[0] = (float)e[0]; qp[1] = (float)e[1]; qp[2] = (float)e[2];
    qp[3] = (float)e[3]; qp[4] = (float)e[4]; qp[5] = (float)sq;
    qp[6] = 0.f; qp[7] = 0.f;
    double* qd = q64 + row * 8;
    qd[0] = e[0]; qd[1] = e[1]; qd[2] = e[2]; qd[3] = e[3]; qd[4] = e[4];
    qd[5] = sq; qd[6] = 0.0; qd[7] = 0.0;
  }
}

__global__ __launch_bounds__(256) void k_fused(
    const u32* flag, const void* fsem, const void* fins, const void* Wad,
    const void* bad, const void* gad, const void* bead, const void* Wins,
    const void* bins, float* q32, double* q64, void* oute_bf, void* oute_f) {
  __shared__ __align__(16) char smem[65536];
  u32 f = *flag;
  if (f == 0)
    fused_body<0>(fsem, fins, Wad, bad, gad, bead, Wins, bins, q32, q64,
                  oute_bf, smem);
  else
    fused_body<1>(fsem, fins, Wad, bad, gad, bead, Wins, bins, q32, q64,
                  oute_f, smem);
}

// ---------------------------------------------------------------------------
// Exact select-NSC via ballot radix descend over 128 packed keys.
// ---------------------------------------------------------------------------
__device__ __forceinline__ void select_core(u64 k0, u64 k1, bool& w0o,
                                            bool& w1o, u32& Pout) {
  u32 d0 = (u32)(k0 >> 32), d1 = (u32)(k1 >> 32);
  bool a0 = true, a1 = true, w0 = false, w1 = false;
  int rank = NSC, asize = 128;
  u32 prefix = 0, fill = 0;
  bool done = false;
#pragma unroll 1
  for (int bit = 31; bit >= 0; --bit) {
    u32 bm = 1u << bit;
    bool z0 = a0 && ((d0 & bm) == 0u);
    bool z1 = a1 && ((d1 & bm) == 0u);
    int c = __popcll(__ballot(z0)) + __popcll(__ballot(z1));
    if (c >= rank) {
      a0 = z0; a1 = z1; asize = c;
    } else {
      rank -= c; w0 = w0 || z0; w1 = w1 || z1;
      a0 = a0 && ((d0 & bm) != 0u); a1 = a1 && ((d1 & bm) != 0u);
      asize -= c; prefix |= bm;
    }
    if (asize == rank) { fill = bm - 1u; done = true; break; }
  }
  if (!done) {  // distance word decided; tie-break on index bits
    u32 m0 = (u32)k0, m1 = (u32)k1;
#pragma unroll 1
    for (int bit = 11; bit >= 0; --bit) {
      u32 bm = 1u << bit;
      bool z0 = a0 && ((m0 & bm) == 0u);
      bool z1 = a1 && ((m1 & bm) == 0u);
      int c = __popcll(__ballot(z0)) + __popcll(__ballot(z1));
      if (c >= rank) {
        a0 = z0; a1 = z1; asize = c;
      } else {
        rank -= c; w0 = w0 || z0; w1 = w1 || z1;
        a0 = a0 && ((m0 & bm) != 0u); a1 = a1 && ((m1 & bm) != 0u);
        asize -= c;
      }
      if (asize == rank) break;
    }
  }
  w0o = w0 || a0;
  w1o = w1 || a1;
  Pout = prefix | fill;
}

__device__ __noinline__ float compress_row(u64* bufr, int lane) {
  u64 k0 = bufr[lane], k1 = bufr[lane + 64];
  bool w0, w1;
  u32 P;
  select_core(k0, k1, w0, w1, P);
  u64 b0 = __ballot(w0), b1 = __ballot(w1);
  int o0 = mbcnt64(b0);
  int o1 = __popcll(b0) + mbcnt64(b1);
  bufr[lane] = ~0ull;
  bufr[lane + 64] = ~0ull;
  if (w0) bufr[o0] = k0;
  if (w1) bufr[o1] = k1;
  return (P >= 0xFF800000u) ? __builtin_inff() : unmonof(P);
}

__device__ __noinline__ void final_row(u64* bufr, int lane,
                                       u16* __restrict__ nnrow) {
  u64 k0 = bufr[lane], k1 = bufr[lane + 64];
  bool w0, w1;
  u32 P;
  select_core(k0, k1, w0, w1, P);
  u64 b0 = __ballot(w0), b1 = __ballot(w1);
  int o0 = mbcnt64(b0);
  int o1 = __popcll(b0) + mbcnt64(b1);
  if (w0) nnrow[o0] = (u16)((u32)k0 & (N_ - 1));
  if (w1) nnrow[o1] = (u16)((u32)k1 & (N_ - 1));
}

// append one 64-candidate batch for row r (wave-uniform helper, inlined)
#define APPEND_BATCH(mk, pr, dd, mm)                                        \
  if (mk) {                                                                 \
    int hc = __popcll(mk);                                                  \
    if (cnt[r] + hc > 128) {                                                \
      t[r] = compress_row(&buf[r][0], lane);                                \
      cnt[r] = NSC;                                                         \
      pr = dd <= t[r];                                                      \
      mk = __ballot(pr);                                                    \
      hc = __popcll(mk);                                                    \
    }                                                                       \
    if (hc) {                                                               \
      int off = mbcnt64(mk);                                                \
      if (pr) buf[r][cnt[r] + off] = ((u64)monof(dd) << 32) | (u32)(mm);    \
      cnt[r] += hc;                                                         \
    }                                                                       \
  }

// ---------------------------------------------------------------------------
// Streaming f32 top-48 screen. One wave = 4 rows, 2 candidates/lane/iter.
// Screen rank value d = sq_m + sum(-2*e_r[i]*e_m[i]) (5-fma chain);
// ordering-equivalent per row; exactness restored by f64 rescore in k_out.
// ---------------------------------------------------------------------------
__global__ __launch_bounds__(256) void k_knn(const float* __restrict__ q32,
                                             u16* __restrict__ nn48) {
  __shared__ u64 bufs[4][ROWS][128];  // 16KB
  int tid = threadIdx.x, wid = tid >> 6, lane = tid & 63;
  int gw = blockIdx.x * 4 + wid;  // 0..8191
  int b = gw >> 10;               // 1024 waves per batch
  int r0 = (gw & 1023) * ROWS;
  const float* qb = q32 + (((size_t)b) << 12) * 8;
  u64(*buf)[128] = bufs[wid];

#pragma unroll
  for (int i = 0; i < 2 * ROWS; ++i) bufs[wid][0][i * 64 + lane] = ~0ull;

  float er2[ROWS][5], t[ROWS];
  int cnt[ROWS];
#pragma unroll
  for (int r = 0; r < ROWS; ++r) {
    const float* qr = qb + (size_t)(r0 + r) * 8;
    er2[r][0] = -2.f * qr[0]; er2[r][1] = -2.f * qr[1];
    er2[r][2] = -2.f * qr[2]; er2[r][3] = -2.f * qr[3];
    er2[r][4] = -2.f * qr[4];
    t[r] = __builtin_inff();
    cnt[r] = 0;
  }

#pragma unroll 1
  for (int g = 0; g < 64; g += 2) {
    int m0 = g * 64 + lane, m1 = m0 + 64;
    float4 A0 = *(const float4*)(qb + (size_t)m0 * 8);
    float2 B0 = *(const float2*)(qb + (size_t)m0 * 8 + 4);
    float4 A1 = *(const float4*)(qb + (size_t)m1 * 8);
    float2 B1 = *(const float2*)(qb + (size_t)m1 * 8 + 4);
#pragma unroll
    for (int r = 0; r < ROWS; ++r) {
      float d0 = B0.y;
      d0 = fmaf(er2[r][0], A0.x, d0);
      d0 = fmaf(er2[r][1], A0.y, d0);
      d0 = fmaf(er2[r][2], A0.z, d0);
      d0 = fmaf(er2[r][3], A0.w, d0);
      d0 = fmaf(er2[r][4], B0.x, d0);
      float d1 = B1.y;
      d1 = fmaf(er2[r][0], A1.x, d1);
      d1 = fmaf(er2[r][1], A1.y, d1);
      d1 = fmaf(er2[r][2], A1.z, d1);
      d1 = fmaf(er2[r][3], A1.w, d1);
      d1 = fmaf(er2[r][4], B1.x, d1);
      bool p0 = d0 <= t[r], p1 = d1 <= t[r];
      u64 mk0 = __ballot(p0), mk1 = __ballot(p1);
      if (mk0 | mk1) {  // wave-uniform; stale-superset appends are safe
        APPEND_BATCH(mk0, p0, d0, m0)
        APPEND_BATCH(mk1, p1, d1, m1)
      }
    }
  }
  u16* nnbase = nn48 + (size_t)(b * N_ + r0) * NSC;
#pragma unroll 1
  for (int r = 0; r < ROWS; ++r) final_row(&buf[r][0], lane, nnbase + r * NSC);
}

// ---------------------------------------------------------------------------
// Per-row (one wave each): f64 rescore of 48 -> top-30 set -> gather/max
// (native-dtype fT, 2 channels/lane) -> W_sem projection (13x4, quad reduce).
// ---------------------------------------------------------------------------
template <int M>
__device__ void out_body(const double* __restrict__ q64,
                         const u16* __restrict__ nn48, const void* fsem,
                         const void* fT, int useFT, const void* Wsem,
                         const void* bsem, void* outv, float* wsm, float* bsm,
                         u32* idxw, float* fls) {
  int tid = threadIdx.x, wid = tid >> 6, lane = tid & 63;
  for (int i = tid; i < 13 * 128; i += 256)
    wsm[(i >> 7) * 132 + (i & 127)] = ldv<M>(Wsem, i);
  if (tid < OSEM) bsm[tid] = ldv<M>(bsem, tid);
  __syncthreads();

  int row = blockIdx.x * 4 + wid;  // 0..32767
  int b = row >> 12, n = row & (N_ - 1);

  // --- f64 rescore of the 48 screened candidates ---
  const double* qdb = q64 + (((size_t)b) << 12) * 8;
  const double* qdr = q64 + (size_t)row * 8;
  double D0 = qdr[0], D1 = qdr[1], D2 = qdr[2], D3 = qdr[3], D4 = qdr[4],
         DS = qdr[5];
  u64 key = ~0ull;
  u32 myid = 0;
  if (lane < NSC) {
    myid = (u32)nn48[(size_t)row * NSC + lane];
    const double* qm = qdb + (size_t)myid * 8;
    double dot = D0 * qm[0];
    dot = fma(D1, qm[1], dot);
    dot = fma(D2, qm[2], dot);
    dot = fma(D3, qm[3], dot);
    dot = fma(D4, qm[4], dot);
    double d = (DS - 2.0 * dot) + qm[5];
    key = (monod(d) & ~0xFFFull) | myid;  // (dist, idx) lexicographic
  }
  int rank = 0;
#pragma unroll 8
  for (int j = 0; j < NSC; ++j) {
    u64 kj = shfl_u64(key, j);
    rank += (kj < key) ? 1 : 0;
  }
  if (lane < NSC && rank < KNN) idxw[wid * 32 + rank] = myid;
  __syncthreads();

  // --- gather/max: lane holds channels {2*lane, 2*lane+1} ---
  float mx0 = -__builtin_inff(), mx1 = -__builtin_inff();
  int c0 = lane * 2;
  if (useFT) {
#pragma unroll 2
    for (int k = 0; k < KNN; ++k) {
      int id = (int)idxw[wid * 32 + k];
      if (M == 0) {
        u32 v = *(const u32*)((const u16*)fT +
                              (size_t)(b * N_ + id) * C_ + c0);
        mx0 = fmaxf(mx0, __uint_as_float(v << 16));
        mx1 = fmaxf(mx1, __uint_as_float(v & 0xFFFF0000u));
      } else {
        float2 v = *(const float2*)((const float*)fT +
                                    (size_t)(b * N_ + id) * C_ + c0);
        mx0 = fmaxf(mx0, v.x);
        mx1 = fmaxf(mx1, v.y);
      }
    }
  } else {
    size_t base = ((size_t)b * C_ + c0) * N_;
#pragma unroll 2
    for (int k = 0; k < KNN; ++k) {
      int id = (int)idxw[wid * 32 + k];
      mx0 = fmaxf(mx0, ldv<M>(fsem, base + id));
      mx1 = fmaxf(mx1, ldv<M>(fsem, base + N_ + id));
    }
  }
  fls[wid * 128 + c0] = mx0;
  fls[wid * 128 + c0 + 1] = mx1;
  __syncthreads();

  // --- projection: lanes (o<13, g<4), 32 channels each, quad shfl reduce ---
  if (lane < 52) {
    int o = lane >> 2, g = lane & 3;
    const float* wr = &wsm[o * 132 + g * 32];
    const float* fr = &fls[wid * 128 + g * 32];
    float s = 0.f;
#pragma unroll
    for (int c = 0; c < 32; ++c) s = fmaf(wr[c], fr[c], s);
    s += __shfl_xor(s, 1, 64);
    s += __shfl_xor(s, 2, 64);
    if (g == 0)
      stv<M>(outv, ((size_t)b * OSEM + o) * N_ + n, s + bsm[o]);
  }
}

__global__ __launch_bounds__(256) void k_out(
    const u32* flag, const double* __restrict__ q64,
    const u16* __restrict__ nn48, const void* fsem, const void* fT,
    int useFT0, int useFT1, const void* Wsem, const void* bsem, void* outv) {
  __shared__ float wsm[13 * 132];
  __shared__ float bsm[16];
  __shared__ u32 idxw[4 * 32];
  __shared__ float fls[4 * 128];
  u32 f = *flag;
  if (f == 0)
    out_body<0>(q64, nn48, fsem, fT, useFT0, Wsem, bsem, outv, wsm, bsm, idxw,
                fls);
  else
    out_body<1>(q64, nn48, fsem, fT, useFT1, Wsem, bsem, outv, wsm, bsm, idxw,
                fls);
}

// ---------------------------------------------------------------------------
extern "C" void kernel_launch(void* const* d_in, const int* in_sizes, int n_in,
                              void* d_out, int out_size, void* d_ws,
                              size_t ws_size, hipStream_t stream) {
  (void)in_sizes; (void)n_in; (void)out_size;
  const void* fsem = d_in[0];
  const void* fins = d_in[1];
  const void* Wad = d_in[2];
  const void* bad = d_in[3];
  const void* gad = d_in[4];
  const void* bead = d_in[5];
  const void* Wins = d_in[6];
  const void* bins = d_in[7];
  const void* Wsem = d_in[8];
  const void* bsem = d_in[9];

  char* ws = (char*)d_ws;
  u32* flag = (u32*)ws;                     // @0
  float* q32 = (float*)(ws + (1 << 20));    // @1MB, 1MB
  double* q64 = (double*)(ws + (2 << 20));  // @2MB, 2MB
  u16* nn48 = (u16*)(ws + (4 << 20));       // @4MB, 3MB (u16 indices)
  void* fT = (void*)(ws + (7 << 20));       // @7MB: bf16 8MB / f32 16MB
  int useFT0 = (ws_size >= (size_t)(15 << 20)) ? 1 : 0;
  int useFT1 = (ws_size >= (size_t)(23 << 20)) ? 1 : 0;

  void* oute_bf = (void*)((u16*)d_out + (size_t)B_ * OSEM * N_);
  void* oute_f32 = (void*)((float*)d_out + (size_t)B_ * OSEM * N_);

  k_sniff<<<1, 64, 0, stream>>>(fsem, flag);
  k_transpose<<<dim3(64, 2, 8), 256, 0, stream>>>(flag, fsem, fT, useFT0,
                                                  useFT1);
  k_fused<<<dim3(64, 8), 256, 0, stream>>>(flag, fsem, fins, Wad, bad, gad,
                                           bead, Wins, bins, q32, q64, oute_bf,
                                           oute_f32);
  k_knn<<<dim3(2048), 256, 0, stream>>>(q32, nn48);
  k_out<<<dim3(8192), 256, 0, stream>>>(flag, q64, nn48, fsem, fT, useFT0,
                                        useFT1, Wsem, bsem, d_out);
}